// Round 3
// baseline (177.421 us; speedup 1.0000x reference)
//
#include <hip/hip_runtime.h>
#include <hip/hip_bf16.h>

#define IS 256
#define NEARV 0.1f
#define FARV 100.0f
#define SLICES 32
#define NTILES 256                 // 16x16 tiles of 16x16 pixels
#define NITEMS (NTILES * SLICES)   // 8192 work items

// ---------------- kernel 1: init ----------------
// d_out is used directly as the z-buffer: raw float bits, atomicMin'd.
// Positive floats compare identically as uints, and every stored depth is in
// (0.1, 100), so uint atomicMin == float min. Init to 100.0f (= FAR).
__global__ void kinit(unsigned int* __restrict__ zb, int* __restrict__ work) {
    int i = blockIdx.x * 256 + threadIdx.x;
    zb[i] = 0x42C80000u;  // __float_as_uint(100.0f)
    if (i == 0) *work = 0;
}

// ---------------- kernel 2: fused persistent raster ----------------
// 2048 persistent blocks pop (tile, slice) items from a global counter.
// Each item: scan its ~157-face range -- gather 3 vertex indices, transform
// vertices on the fly (verts: 30KB, L1-resident; redundancy across tiles is
// ~4us of VALU device-wide), cull (front/area), tile-bbox test, compact
// survivors into LDS -- then all 256 pixel-threads evaluate the compacted
// list and atomicMin the tile's pixels. Arithmetic is bit-identical to the
// round-1 kernel (absmax was 0.0).
__launch_bounds__(256, 8)
__global__ void kraster(const float* __restrict__ verts, const int* __restrict__ faces,
                        unsigned int* __restrict__ zb, int* __restrict__ work, int nf) {
    __shared__ __align__(16) float sf[256 * 12];
    __shared__ int scount;
    __shared__ int sitem;

    const int tid = threadIdx.x;
    const int tx = tid & 15;
    const int ty = tid >> 4;
    const int per = (nf + SLICES - 1) / SLICES;  // 157 for nf=5000 (<=256: one chunk)

    for (;;) {
        if (tid == 0) {
            sitem = atomicAdd(work, 1);
            scount = 0;
        }
        __syncthreads();
        const int item = sitem;
        if (item >= NITEMS) break;  // block-uniform
        // item & 255 = tile (so center tiles -- the hot ones -- pop early and
        // concurrent blocks share the same face range in L1/L2)
        const int tile = item & (NTILES - 1);
        const int slice = item >> 8;
        const int bx = tile & 15;
        const int by = tile >> 4;
        const int j = bx * 16 + tx;
        const int i = by * 16 + ty;
        // pixel centers: (2*idx + 1 - 256)/256 (exact in fp32)
        const float px = ((float)(2 * j + 1) - 256.0f) * (1.0f / 256.0f);
        const float py = ((float)(2 * i + 1) - 256.0f) * (1.0f / 256.0f);
        const float px_lo = ((float)(2 * (bx * 16) + 1) - 256.0f) * (1.0f / 256.0f);
        const float px_hi = px_lo + 30.0f / 256.0f;
        const float py_lo = ((float)(2 * (by * 16) + 1) - 256.0f) * (1.0f / 256.0f);
        const float py_hi = py_lo + 30.0f / 256.0f;

        const int f0 = slice * per;
        const int f1 = min(nf, f0 + per);

        float maxinv = 0.0f;

        for (int base = f0; base < f1; base += 256) {  // block-uniform trip count
            int f = base + tid;
            if (f < f1) {
                int i0 = faces[f * 3 + 0];
                int i1 = faces[f * 3 + 1];
                int i2 = faces[f * 3 + 2];
                // transform all three vertices (identical arithmetic to r1 kv_transform)
                float z0 = verts[i0 * 3 + 2] + 2.7320508075688772f;
                float z1 = verts[i1 * 3 + 2] + 2.7320508075688772f;
                float z2 = verts[i2 * 3 + 2] + 2.7320508075688772f;
                bool front = (z0 > NEARV) && (z1 > NEARV) && (z2 > NEARV);
                float zs0 = (fabsf(z0) < 1e-5f) ? 1e-5f : z0;
                float zs1 = (fabsf(z1) < 1e-5f) ? 1e-5f : z1;
                float zs2 = (fabsf(z2) < 1e-5f) ? 1e-5f : z2;
                float d0 = zs0 * 0.57735026918962576f;
                float d1 = zs1 * 0.57735026918962576f;
                float d2 = zs2 * 0.57735026918962576f;
                float x0 = verts[i0 * 3 + 0] / d0;
                float y0 = verts[i0 * 3 + 1] / d0;
                float x1 = verts[i1 * 3 + 0] / d1;
                float y1 = verts[i1 * 3 + 1] / d1;
                float x2 = verts[i2 * 3 + 0] / d2;
                float y2 = verts[i2 * 3 + 1] / d2;
                float area = (x1 - x0) * (y2 - y0) - (x2 - x0) * (y1 - y0);
                if (front && (fabsf(area) > 1e-8f)) {
                    float xmin = fminf(x0, fminf(x1, x2));
                    float xmax = fmaxf(x0, fmaxf(x1, x2));
                    float ymin = fminf(y0, fminf(y1, y2));
                    float ymax = fmaxf(y0, fmaxf(y1, y2));
                    if (xmin <= px_hi && xmax >= px_lo && ymin <= py_hi && ymax >= py_lo) {
                        float ia = 1.0f / area;
                        float iz0 = 1.0f / fmaxf(z0, 1e-4f);
                        float iz1 = 1.0f / fmaxf(z1, 1e-4f);
                        float iz2 = 1.0f / fmaxf(z2, 1e-4f);
                        int k = atomicAdd(&scount, 1);
                        float4* q = (float4*)(sf + k * 12);  // 48B stride, 16B aligned
                        q[0] = make_float4(x0, y0, x1, y1);
                        q[1] = make_float4(x2, y2, ia, iz0);
                        q[2] = make_float4(iz1, iz2, 0.0f, 0.0f);
                    }
                }
            }
            __syncthreads();
            const int m = scount;
#pragma unroll 2
            for (int k = 0; k < m; ++k) {
                const float4* q = (const float4*)(sf + k * 12);  // uniform addr -> broadcast
                float4 a0 = q[0];
                float4 a1 = q[1];
                float4 a2 = q[2];
                float dx0 = a0.x - px, dy0 = a0.y - py;
                float dx1 = a0.z - px, dy1 = a0.w - py;
                float dx2 = a1.x - px, dy2 = a1.y - py;
                float e0 = dx1 * dy2 - dx2 * dy1;
                float e1 = dx2 * dy0 - dx0 * dy2;
                float w0 = e0 * a1.z;
                float w1 = e1 * a1.z;
                float w2 = 1.0f - w0 - w1;
                float invz = w0 * a1.w + w1 * a2.x + w2 * a2.y;
                float invzc = fmaxf(invz, 1e-6f);
                // zp = 1/invzc; valid iff inside && NEAR < zp < FAR <=> 0.01 < invzc < 10
                bool ok = (w0 >= 0.0f) && (w1 >= 0.0f) && (w2 >= 0.0f) &&
                          (invzc < 10.0f) && (invzc > 0.01f);
                if (ok) maxinv = fmaxf(maxinv, invzc);
            }
            __syncthreads();  // protect sf/scount before next chunk / next pop
            if (tid == 0) scount = 0;
        }
        if (maxinv > 0.0f) {
            float zp = 1.0f / maxinv;  // correctly-rounded 1/x is monotone => min-exact
            atomicMin(&zb[i * IS + j], __float_as_uint(zp));
        }
        // next pop's barrier protects sitem reuse
    }
}

extern "C" void kernel_launch(void* const* d_in, const int* in_sizes, int n_in,
                              void* d_out, int out_size, void* d_ws, size_t ws_size,
                              hipStream_t stream) {
    const float* verts = (const float*)d_in[0];
    const int* faces = (const int*)d_in[1];
    unsigned int* zb = (unsigned int*)d_out;  // float bits, min'd in place

    const int nf = in_sizes[1] / 3;  // 5000

    int* work = (int*)d_ws;  // pop counter

    kinit<<<(IS * IS) / 256, 256, 0, stream>>>(zb, work);
    kraster<<<2048, 256, 0, stream>>>(verts, faces, zb, work, nf);
}